// Round 10
// baseline (232.712 us; speedup 1.0000x reference)
//
#include <hip/hip_runtime.h>

typedef __attribute__((ext_vector_type(8))) short short8;
typedef __attribute__((ext_vector_type(8))) __bf16 bf16x8;
typedef __attribute__((ext_vector_type(4))) float f32x4;
typedef __attribute__((ext_vector_type(4))) unsigned short ushort4_t;
typedef __attribute__((ext_vector_type(4))) unsigned int uint4_t;
typedef __attribute__((ext_vector_type(2))) unsigned int uint2_t;

#define NB   4096
#define NIN  4096
#define NX   4098
#define NC   128
#define NO   64
#define NA   64
#define NOUT 1024
#define NROW (NC * NO)

__device__ __forceinline__ unsigned short f2bf(float f) {
  unsigned b = __builtin_bit_cast(unsigned, f);
  b += 0x7FFFu + ((b >> 16) & 1u);
  return (unsigned short)(b >> 16);
}
__device__ __forceinline__ float bf2f(unsigned short u) {
  return __builtin_bit_cast(float, (unsigned)u << 16);
}
// f32 -> e4m3fn: RNE, FTZ below 2^-6, clamp 448. (R4/R9-verified)
__device__ __forceinline__ unsigned f2e4m3(float f) {
  unsigned u = __builtin_bit_cast(unsigned, f);
  unsigned s = (u >> 24) & 0x80u;
  unsigned mag = u & 0x7fffffffu;
  mag = mag > 0x43E00000u ? 0x43E00000u : mag;
  unsigned r = mag + 0x7FFFFu + ((mag >> 20) & 1u);
  int e = (int)(r >> 23) - 120;
  unsigned v = (e <= 0) ? 0u : (((unsigned)e << 3) | ((r >> 20) & 7u));
  return v | s;
}
__device__ __forceinline__ unsigned e4m32bf(unsigned f) {
  unsigned t = (((f & 0x7Fu) << 4) + 0x3C00u) | ((f & 0x80u) << 8);
  return (f & 0x78u) ? t : 0u;
}
__device__ __forceinline__ uint4_t dec8(uint2_t d) {
  uint4_t o;
#pragma unroll
  for (int k = 0; k < 4; ++k) {
    unsigned src = (k < 2) ? d[0] : d[1];
    unsigned sh = (k & 1) * 16;
    unsigned b0 = (src >> sh) & 0xFFu;
    unsigned b1 = (src >> (sh + 8)) & 0xFFu;
    o[k] = e4m32bf(b0) | (e4m32bf(b1) << 16);
  }
  return o;
}

// ---------------------------------------------------------------------------
// prep: transpose x (B x NIN f32) -> xT8 (NX x NB fp8), W -> bf16, const rows.
// ---------------------------------------------------------------------------
__global__ __launch_bounds__(256) void prep_kernel(
    const float* __restrict__ x, const float* __restrict__ W,
    unsigned char* __restrict__ xT8, unsigned short* __restrict__ Wb) {
  int bid = blockIdx.x, t = threadIdx.x;
  if (bid < 4096) {
    __shared__ unsigned short tile[64][68];
    int b0 = (bid >> 6) << 6, n0 = (bid & 63) << 6;
    int r = t >> 4, c4 = (t & 15) << 2;
#pragma unroll
    for (int rr = 0; rr < 4; ++rr) {
      int row = r + rr * 16;
      float4 v = *(const float4*)(x + (size_t)(b0 + row) * NIN + n0 + c4);
      tile[row][c4 + 0] = f2bf(v.x);
      tile[row][c4 + 1] = f2bf(v.y);
      tile[row][c4 + 2] = f2bf(v.z);
      tile[row][c4 + 3] = f2bf(v.w);
    }
    __syncthreads();
#pragma unroll
    for (int rr = 0; rr < 4; ++rr) {
      int nl = r + rr * 16;
      unsigned pk = f2e4m3(bf2f(tile[c4 + 0][nl])) |
                    (f2e4m3(bf2f(tile[c4 + 1][nl])) << 8) |
                    (f2e4m3(bf2f(tile[c4 + 2][nl])) << 16) |
                    (f2e4m3(bf2f(tile[c4 + 3][nl])) << 24);
      *(unsigned*)(xT8 + (size_t)(n0 + nl) * NB + b0 + c4) = pk;
    }
  } else if (bid < 4096 + 256) {
    size_t i0 = (size_t)(bid - 4096) * 2048 + (size_t)t * 8;
    float4 v0 = *(const float4*)(W + i0);
    float4 v1 = *(const float4*)(W + i0 + 4);
    ushort4_t a, b;
    a.x = f2bf(v0.x); a.y = f2bf(v0.y); a.z = f2bf(v0.z); a.w = f2bf(v0.w);
    b.x = f2bf(v1.x); b.y = f2bf(v1.y); b.z = f2bf(v1.z); b.w = f2bf(v1.w);
    *(ushort4_t*)(Wb + i0) = a;
    *(ushort4_t*)(Wb + i0 + 4) = b;
  } else {
    // const rows 4096 (zero) / 4097 (one): 2 blocks, 16B per thread
    int row = bid - 4352;
    unsigned val = row ? 0x38383838u : 0u;  // fp8 1.0 = 0x38
    uint4_t o = {val, val, val, val};
    *(uint4_t*)(xT8 + (size_t)(NIN + row) * NB + t * 16) = o;
  }
}

// ---------------------------------------------------------------------------
// masks: gmask[r]=1 iff buffer row r is re-gathered; omask[r]=1 iff final
// gather reads row r.
// ---------------------------------------------------------------------------
__global__ __launch_bounds__(1024) void mask_kernel(
    const int* __restrict__ axon, const int* __restrict__ oidx,
    unsigned char* __restrict__ gmask, unsigned char* __restrict__ omask) {
  int t = threadIdx.x;
  for (int i = t; i < NROW; i += 1024) { gmask[i] = 0; omask[i] = 0; }
  __syncthreads();
  for (int i = t; i < NC * NA; i += 1024) {
    int idx = axon[i];
    if (idx >= NX) gmask[idx - NX] = 1;
  }
  if (t < NOUT) {
    int idx = oidx[t];
    if (idx >= NX) omask[idx - NX] = 1;
  }
}

// ---------------------------------------------------------------------------
// cycle v10: v7 skeleton, fp8 storage. BT=512, 512 thr (8 waves), grid (8,128)
// -> b-tile pinned to XCD; per-XCD L2 working set = xT8 slice 2.1MB + fp8
// ping/pong ~2.1MB ~= 4MB L2.
// Stage: wave-uniform row ptrs, 512B contiguous fp8 reads, dec8 -> reg 8x8
// transpose -> swizzled LDS [b][a] bf16 (addr_u16(b,a)=b*64+((a>>3)^(b&7)^
// ((b>>5)&7))*8+(a&7)). MFMA per wave over 64 b.
// Epilogue MODE 0: pack fp8 rows in LDS -> full-line 512B row stores, gmask.
// Epilogue MODE 1: bf16 rows -> bufD [row][b], omask rows only.
// ---------------------------------------------------------------------------
template <int MODE>
__global__ __launch_bounds__(512) void cycle_kernel(
    const unsigned char* __restrict__ xT8, const unsigned short* __restrict__ Wb,
    const unsigned char* __restrict__ buf8p, unsigned char* __restrict__ buf8n,
    unsigned short* __restrict__ bufD, const int* __restrict__ axon,
    const unsigned char* __restrict__ mask, int first) {
  __shared__ __align__(16) unsigned short SM[64 * 520];  // 66.6 KiB
  int bt = blockIdx.x, c = blockIdx.y;
  int t = threadIdx.x;
  int b0 = bt << 9;
  int lane = t & 63, w = t >> 6;
  int ln = lane & 15, g = lane >> 4;
  const int* arow = axon + (c << 6);

  // ---- stage: wave w owns rows a = w*8..w*8+7; lane covers b = lane*8..+7
  {
    uint4_t rbf[8];
#pragma unroll
    for (int r = 0; r < 8; ++r) {
      int idx = arow[w * 8 + r];
      const unsigned char* s = nullptr;
      if (idx < NX)      s = xT8 + (size_t)idx * NB;
      else if (!first)   s = buf8p + (size_t)(idx - NX) * NB;
      if (s) rbf[r] = dec8(*(const uint2_t*)(s + b0 + lane * 8));
      else   rbf[r] = (uint4_t)(0u);
    }
    unsigned lo[4][4], hi[4][4];
#pragma unroll
    for (int p = 0; p < 4; ++p)
#pragma unroll
      for (int k = 0; k < 4; ++k) {
        unsigned wi = rbf[2 * p][k], wj = rbf[2 * p + 1][k];
        lo[p][k] = __builtin_amdgcn_perm(wj, wi, 0x05040100u);
        hi[p][k] = __builtin_amdgcn_perm(wj, wi, 0x07060302u);
      }
#pragma unroll
    for (int e = 0; e < 8; ++e) {
      int k = e >> 1;
      uint4_t col;
      if (e & 1) { col[0] = hi[0][k]; col[1] = hi[1][k]; col[2] = hi[2][k]; col[3] = hi[3][k]; }
      else       { col[0] = lo[0][k]; col[1] = lo[1][k]; col[2] = lo[2][k]; col[3] = lo[3][k]; }
      int b = lane * 8 + e;
      int sw = w ^ (b & 7) ^ ((b >> 5) & 7);
      *(uint4_t*)&SM[b * 64 + (sw << 3)] = col;
    }
  }
  __syncthreads();

  // ---- compute: wave w covers b-local [w*64, w*64+64) ----
  const unsigned short* wrow = Wb + ((size_t)c << 12);
  bool grp[4];
#pragma unroll
  for (int j = 0; j < 4; ++j) {
    if (MODE == 1) grp[j] = __any((int)(mask[(c << 6) + j * 16 + ln] != 0));
    else           grp[j] = true;
  }

  f32x4 acc[4][4];
#pragma unroll
  for (int i = 0; i < 4; ++i)
#pragma unroll
    for (int j = 0; j < 4; ++j) acc[i][j] = (f32x4)(0.f);

#pragma unroll
  for (int ks = 0; ks < 2; ++ks) {
    short8 ag[4];
#pragma unroll
    for (int i = 0; i < 4; ++i) {
      int bl = (w << 6) + (i << 4) + ln;
      int c8 = (ks << 2) + g;
      int sw = c8 ^ (bl & 7) ^ ((bl >> 5) & 7);
      ag[i] = *(const short8*)&SM[bl * 64 + (sw << 3)];
    }
#pragma unroll
    for (int j = 0; j < 4; ++j) {
      if (!grp[j]) continue;
      short8 bw = *(const short8*)(wrow + ((size_t)(j * 16 + ln) << 6) + ks * 32 + g * 8);
#pragma unroll
      for (int i = 0; i < 4; ++i)
        acc[i][j] = __builtin_amdgcn_mfma_f32_16x16x32_bf16(
            __builtin_bit_cast(bf16x8, ag[i]), __builtin_bit_cast(bf16x8, bw),
            acc[i][j], 0, 0, 0);
    }
  }

  // ---- epilogue ----
  __syncthreads();  // MFMA reads of G done; reuse SM
  if (MODE == 0) {
    unsigned char* SM8 = (unsigned char*)SM;
    // frag(i,j): lane holds o=j*16+ln, b-local = w*64+i*16+g*4+{0..3}
#pragma unroll
    for (int j = 0; j < 4; ++j) {
      int o = j * 16 + ln;
#pragma unroll
      for (int i = 0; i < 4; ++i) {
        unsigned pk = 0;
#pragma unroll
        for (int r = 0; r < 4; ++r)
          pk |= f2e4m3(fmaxf(acc[i][j][r], 0.f)) << (r * 8);
        *(unsigned*)&SM8[o * 528 + (w << 6) + (i << 4) + (g << 2)] = pk;
      }
    }
    __syncthreads();
    // wave w stores rows {it*8+w}: 64 lanes x 8B = 512B contiguous (4 lines)
#pragma unroll
    for (int it = 0; it < 8; ++it) {
      int row = it * 8 + w;
      if (mask[(c << 6) + row] == 0) continue;  // wave-uniform skip
      uint2_t v = *(const uint2_t*)&SM8[row * 528 + lane * 8];
      *(uint2_t*)(buf8n + ((size_t)((c << 6) + row)) * NB + b0 + lane * 8) = v;
    }
  } else {
#pragma unroll
    for (int j = 0; j < 4; ++j) {
      int o = j * 16 + ln;
#pragma unroll
      for (int i = 0; i < 4; ++i) {
        ushort4_t pk;
#pragma unroll
        for (int r = 0; r < 4; ++r) pk[r] = f2bf(fmaxf(acc[i][j][r], 0.f));
        *(ushort4_t*)&SM[o * 520 + (w << 6) + (i << 4) + (g << 2)] = pk;
      }
    }
    __syncthreads();
#pragma unroll
    for (int it = 0; it < 8; ++it) {
      int row = it * 8 + w;
      int r = (c << 6) + row;
      if (mask[r] == 0) continue;
      uint4_t v = *(const uint4_t*)&SM[row * 520 + (lane << 3)];
      *(uint4_t*)(bufD + (size_t)r * NB + b0 + (lane << 3)) = v;
    }
  }
}

// ---------------------------------------------------------------------------
// final: dynamic j from bufD (bf16, LDS transpose); static j straight from x
// (exact f32); const rows 0/1. (R9-verified)
// ---------------------------------------------------------------------------
__global__ __launch_bounds__(256) void final_kernel(
    const float* __restrict__ x, const unsigned short* __restrict__ bufD,
    const int* __restrict__ out_idx, float* __restrict__ out) {
  __shared__ unsigned short tile[256][66];
  int j0 = blockIdx.x << 6, b0 = blockIdx.y << 8;
  int t = threadIdx.x;
  {
    int jl = t >> 2, bq = t & 3;
    int idx = out_idx[j0 + jl];
    if (idx >= NX) {
      const unsigned short* src = bufD + (size_t)(idx - NX) * NB;
      int jcol = jl ^ (bq << 4);
#pragma unroll
      for (int k = 0; k < 8; ++k) {
        short8 v = *(const short8*)(src + b0 + bq * 64 + k * 8);
#pragma unroll
        for (int m = 0; m < 8; ++m)
          tile[bq * 64 + k * 8 + m][jcol] = (unsigned short)v[m];
      }
    }
  }
  __syncthreads();
  {
    int j = t & 63, ws = t >> 6;
    int idx = out_idx[j0 + j];
    bool dyn = idx >= NX;
    float cv = (idx == NIN + 1) ? 1.f : 0.f;
    bool isx = idx < NIN;
#pragma unroll
    for (int bb = 0; bb < 64; ++bb) {
      int b = bb * 4 + ws;
      float val;
      if (dyn) {
        int jc = j ^ ((b >> 6) << 4);
        val = bf2f(tile[b][jc]);
      } else if (isx) {
        val = x[(size_t)(b0 + b) * NIN + idx];
      } else {
        val = cv;
      }
      out[(size_t)(b0 + b) * NOUT + j0 + j] = val;
    }
  }
}

// ---------------------------------------------------------------------------
extern "C" void kernel_launch(void* const* d_in, const int* in_sizes, int n_in,
                              void* d_out, int out_size, void* d_ws, size_t ws_size,
                              hipStream_t stream) {
  const float* x    = (const float*)d_in[0];
  const float* W    = (const float*)d_in[1];
  const int*   axon = (const int*)d_in[2];
  const int*   oidx = (const int*)d_in[3];
  float* out = (float*)d_out;

  const size_t XT8_B  = (size_t)NX * NB;          // 16,785,408
  const size_t WB_B   = (size_t)NC * NO * NA * 2; //  1,048,576
  const size_t BUF8_B = (size_t)NROW * NB;        // 33,554,432
  const size_t BUFD_B = (size_t)NROW * NB * 2;    // 67,108,864
  const size_t MASK_B = 8192;
  if (ws_size < XT8_B + WB_B + 2 * BUF8_B + BUFD_B + 2 * MASK_B) return; // ~152MB

  char* p = (char*)d_ws;
  unsigned char*  xT8   = (unsigned char*)p;   p += XT8_B;
  unsigned short* Wb    = (unsigned short*)p;  p += WB_B;
  unsigned char*  buf8A = (unsigned char*)p;   p += BUF8_B;
  unsigned char*  buf8B = (unsigned char*)p;   p += BUF8_B;
  unsigned short* bufD  = (unsigned short*)p;  p += BUFD_B;
  unsigned char*  gmask = (unsigned char*)p;   p += MASK_B;
  unsigned char*  omask = (unsigned char*)p;

  prep_kernel<<<4354, 256, 0, stream>>>(x, W, xT8, Wb);
  mask_kernel<<<1, 1024, 0, stream>>>(axon, oidx, gmask, omask);
  dim3 cg(NB / 512, NC);  // (8, 128): b-tile -> XCD
  cycle_kernel<0><<<cg, 512, 0, stream>>>(xT8, Wb, buf8B, buf8A, bufD, axon, gmask, 1);
  cycle_kernel<0><<<cg, 512, 0, stream>>>(xT8, Wb, buf8A, buf8B, bufD, axon, gmask, 0);
  cycle_kernel<0><<<cg, 512, 0, stream>>>(xT8, Wb, buf8B, buf8A, bufD, axon, gmask, 0);
  cycle_kernel<1><<<cg, 512, 0, stream>>>(xT8, Wb, buf8A, buf8B, bufD, axon, omask, 0);
  final_kernel<<<dim3(NOUT / 64, NB / 256), 256, 0, stream>>>(x, bufD, oidx, out);
}

// Round 11
// 166.335 us; speedup vs baseline: 1.3991x; 1.3991x over previous
//
#include <hip/hip_runtime.h>

typedef __attribute__((ext_vector_type(8))) short short8;
typedef __attribute__((ext_vector_type(8))) __bf16 bf16x8;
typedef __attribute__((ext_vector_type(4))) float f32x4;
typedef __attribute__((ext_vector_type(4))) unsigned short ushort4_t;
typedef __attribute__((ext_vector_type(4))) unsigned int uint4_t;
typedef __attribute__((ext_vector_type(2))) unsigned int uint2_t;

#define NB   4096
#define NIN  4096
#define NX   4098
#define NC   128
#define NO   64
#define NA   64
#define NOUT 1024
#define NROW (NC * NO)

__device__ __forceinline__ unsigned short f2bf(float f) {
  unsigned b = __builtin_bit_cast(unsigned, f);
  b += 0x7FFFu + ((b >> 16) & 1u);
  return (unsigned short)(b >> 16);
}
__device__ __forceinline__ float bf2f(unsigned short u) {
  return __builtin_bit_cast(float, (unsigned)u << 16);
}

// ---------------------------------------------------------------------------
// prep: transpose x -> xT (bf16), W -> bf16, const rows. (R8-verified)
// ---------------------------------------------------------------------------
__global__ __launch_bounds__(256) void prep_kernel(
    const float* __restrict__ x, const float* __restrict__ W,
    unsigned short* __restrict__ xT, unsigned short* __restrict__ Wb) {
  int bid = blockIdx.x, t = threadIdx.x;
  if (bid < 4096) {
    __shared__ unsigned short tile[64][68];
    int b0 = (bid >> 6) << 6, n0 = (bid & 63) << 6;
    int r = t >> 4, c4 = (t & 15) << 2;
#pragma unroll
    for (int rr = 0; rr < 4; ++rr) {
      int row = r + rr * 16;
      float4 v = *(const float4*)(x + (size_t)(b0 + row) * NIN + n0 + c4);
      tile[row][c4 + 0] = f2bf(v.x);
      tile[row][c4 + 1] = f2bf(v.y);
      tile[row][c4 + 2] = f2bf(v.z);
      tile[row][c4 + 3] = f2bf(v.w);
    }
    __syncthreads();
#pragma unroll
    for (int rr = 0; rr < 4; ++rr) {
      int nl = r + rr * 16;
      ushort4_t o;
      o.x = tile[c4 + 0][nl];
      o.y = tile[c4 + 1][nl];
      o.z = tile[c4 + 2][nl];
      o.w = tile[c4 + 3][nl];
      *(ushort4_t*)(xT + (size_t)(n0 + nl) * NB + b0 + c4) = o;
    }
  } else if (bid < 4096 + 256) {
    size_t i0 = (size_t)(bid - 4096) * 2048 + (size_t)t * 8;
    float4 v0 = *(const float4*)(W + i0);
    float4 v1 = *(const float4*)(W + i0 + 4);
    ushort4_t a, b;
    a.x = f2bf(v0.x); a.y = f2bf(v0.y); a.z = f2bf(v0.z); a.w = f2bf(v0.w);
    b.x = f2bf(v1.x); b.y = f2bf(v1.y); b.z = f2bf(v1.z); b.w = f2bf(v1.w);
    *(ushort4_t*)(Wb + i0) = a;
    *(ushort4_t*)(Wb + i0 + 4) = b;
  } else {
    int e = (bid - 4352) * 1024 + t * 4;
    int row = e >> 12, col = e & 4095;
    unsigned short val = (row == 0) ? (unsigned short)0 : (unsigned short)0x3F80;
    ushort4_t o = {val, val, val, val};
    *(ushort4_t*)(xT + (size_t)(NIN + row) * NB + col) = o;
  }
}

__global__ __launch_bounds__(1024) void mask_kernel(
    const int* __restrict__ axon, const int* __restrict__ oidx,
    unsigned char* __restrict__ gmask, unsigned char* __restrict__ omask) {
  int t = threadIdx.x;
  for (int i = t; i < NROW; i += 1024) { gmask[i] = 0; omask[i] = 0; }
  __syncthreads();
  for (int i = t; i < NC * NA; i += 1024) {
    int idx = axon[i];
    if (idx >= NX) gmask[idx - NX] = 1;
  }
  if (t < NOUT) {
    int idx = oidx[t];
    if (idx >= NX) omask[idx - NX] = 1;
  }
}

// ---------------------------------------------------------------------------
// cycle v11: R8 skeleton + 2-chunk software pipeline.
// BT=512 per block as 2 chunks of 256 b; 512 thr (8 waves); grid (8,128)
// (b-tile -> XCD). Two 32 KB LDS G-tiles (R0,R1) double-buffer the chunks;
// each is reused as the epilogue OS tile after its MFMA barrier.
// Schedule: load0 -> R0 | bar | issue load1 | MFMA0 | bar | epi0+stores0 |
// transpose1 -> R1 (counted vmcnt; stores0 in flight) | bar | MFMA1 | bar |
// epi1+stores1.  All bf16.
// G layout (verified): addr_u16(b,a) = b*64 + ((a>>3)^(b&7)^((b>>5)&7))*8 + (a&7)
// OS layout: byte = o*512 + inner ^ ((o&7)<<4)  (row-local XOR swizzle)
// MODE 0: store gmask rows. MODE 1: store omask rows + skip empty o-groups.
// ---------------------------------------------------------------------------
template <int MODE>
__global__ __launch_bounds__(512, 4) void cycle_kernel(
    const unsigned short* __restrict__ xT, const unsigned short* __restrict__ Wb,
    const unsigned short* __restrict__ bufPrev, unsigned short* __restrict__ bufNext,
    const int* __restrict__ axon, const unsigned char* __restrict__ mask,
    int first) {
  __shared__ __align__(16) unsigned short R0[128 * 128];  // 32 KiB
  __shared__ __align__(16) unsigned short R1[128 * 128];  // 32 KiB
  int c = blockIdx.y;
  int t = threadIdx.x;
  int b0 = blockIdx.x << 9;
  int lane = t & 63, w = t >> 6;
  int ln = lane & 15, g = lane >> 4;
  int g5 = t >> 5, lane5 = t & 31;
  int ao = g5 >> 1, h = g5 & 1;
  const int* arow = axon + (c << 6);

  // 4 row pointers per thread (rows g5*4 .. g5*4+3)
  const unsigned short* src[4];
#pragma unroll
  for (int r = 0; r < 4; ++r) {
    int idx = arow[g5 * 4 + r];
    const unsigned short* s = nullptr;
    if (idx < NX)      s = xT + (size_t)idx * NB;
    else if (!first)   s = bufPrev + (size_t)(idx - NX) * NB;
    src[r] = s;
  }

  const unsigned short* wrow = Wb + ((size_t)c << 12);
  bool grp[4];
#pragma unroll
  for (int j = 0; j < 4; ++j)
    grp[j] = (MODE == 1) ? __any((int)(mask[(c << 6) + j * 16 + ln] != 0)) : true;

  // 4x8 register transpose -> swizzled G write (b64, effectively conflict-free)
  auto transpose_write = [&](unsigned short* Rk, uint4_t* L) {
#pragma unroll
    for (int k = 0; k < 4; ++k) {
      unsigned lo01 = __builtin_amdgcn_perm(L[1][k], L[0][k], 0x05040100u);
      unsigned hi01 = __builtin_amdgcn_perm(L[1][k], L[0][k], 0x07060302u);
      unsigned lo23 = __builtin_amdgcn_perm(L[3][k], L[2][k], 0x05040100u);
      unsigned hi23 = __builtin_amdgcn_perm(L[3][k], L[2][k], 0x07060302u);
#pragma unroll
      for (int hb = 0; hb < 2; ++hb) {
        int bl = lane5 * 8 + 2 * k + hb;
        int sw = ao ^ (bl & 7) ^ ((bl >> 5) & 7);
        uint2_t col;
        col[0] = hb ? hi01 : lo01;
        col[1] = hb ? hi23 : lo23;
        *(uint2_t*)&Rk[bl * 64 + (sw << 3) + (h << 2)] = col;
      }
    }
  };

  auto compute = [&](const unsigned short* Rk, f32x4 (&acc)[2][4]) {
#pragma unroll
    for (int i = 0; i < 2; ++i)
#pragma unroll
      for (int j = 0; j < 4; ++j) acc[i][j] = (f32x4)(0.f);
#pragma unroll
    for (int ks = 0; ks < 2; ++ks) {
      short8 ag[2];
#pragma unroll
      for (int i = 0; i < 2; ++i) {
        int bl = (w << 5) + (i << 4) + ln;
        int c8 = (ks << 2) + g;
        int sw = c8 ^ (bl & 7) ^ ((bl >> 5) & 7);
        ag[i] = *(const short8*)&Rk[bl * 64 + (sw << 3)];
      }
#pragma unroll
      for (int j = 0; j < 4; ++j) {
        if (MODE == 1 && !grp[j]) continue;
        short8 bw = *(const short8*)(wrow + ((size_t)(j * 16 + ln) << 6) + ks * 32 + g * 8);
#pragma unroll
        for (int i = 0; i < 2; ++i)
          acc[i][j] = __builtin_amdgcn_mfma_f32_16x16x32_bf16(
              __builtin_bit_cast(bf16x8, ag[i]), __builtin_bit_cast(bf16x8, bw),
              acc[i][j], 0, 0, 0);
      }
    }
  };

  // epilogue: acc -> OS (row-swizzled) -> barrier -> full-line row stores
  auto epilogue = [&](unsigned short* Rk, f32x4 (&acc)[2][4], int ck) {
    char* OS = (char*)Rk;
#pragma unroll
    for (int j = 0; j < 4; ++j) {
      int o = j * 16 + ln;
      int sz = (o & 7) << 4;
#pragma unroll
      for (int i = 0; i < 2; ++i) {
        ushort4_t pk;
#pragma unroll
        for (int r = 0; r < 4; ++r) pk[r] = f2bf(fmaxf(acc[i][j][r], 0.f));
        int inner = (w << 6) + (i << 5) + (g << 3);
        *(ushort4_t*)(OS + o * 512 + (inner ^ sz)) = pk;
      }
    }
    __syncthreads();
#pragma unroll
    for (int it = 0; it < 8; ++it) {
      int row = it * 8 + w;
      if (mask[(c << 6) + row] == 0) continue;  // wave-uniform skip
      ushort4_t v = *(const ushort4_t*)(OS + row * 512 + ((lane * 8) ^ ((row & 7) << 4)));
      *(ushort4_t*)(bufNext + ((size_t)((c << 6) + row)) * NB + b0 + ck * 256 + (lane << 2)) = v;
    }
  };

  const uint4_t Z = (uint4_t)0u;
  f32x4 acc[2][4];

  // ---- chunk 0: load + transpose -> R0
  uint4_t L0[4];
#pragma unroll
  for (int r = 0; r < 4; ++r)
    L0[r] = src[r] ? *(const uint4_t*)(src[r] + b0 + lane5 * 8) : Z;
  transpose_write(R0, L0);
  __syncthreads();

  // ---- issue chunk 1 loads (in flight across MFMA0 + epi0)
  uint4_t L1[4];
#pragma unroll
  for (int r = 0; r < 4; ++r)
    L1[r] = src[r] ? *(const uint4_t*)(src[r] + b0 + 256 + lane5 * 8) : Z;

  // ---- chunk 0 compute + epilogue
  compute(R0, acc);
  __syncthreads();          // all MFMA reads of R0 done
  epilogue(R0, acc, 0);     // stores0 fire-and-forget

  // ---- chunk 1: transpose (waits L1 via counted vmcnt) + compute + epilogue
  transpose_write(R1, L1);
  __syncthreads();
  compute(R1, acc);
  __syncthreads();
  epilogue(R1, acc, 1);
}

// ---------------------------------------------------------------------------
// final (R8-verified): out[b][j] = f32(pool[out_idx[j]][b]); LDS transpose.
// ---------------------------------------------------------------------------
__global__ __launch_bounds__(256) void final_kernel(
    const unsigned short* __restrict__ xT, const unsigned short* __restrict__ bufFin,
    const int* __restrict__ out_idx, float* __restrict__ out) {
  __shared__ unsigned short tile[256][66];
  int j0 = blockIdx.x << 6, b0 = blockIdx.y << 8;
  int t = threadIdx.x;
  {
    int jl = t >> 2, bq = t & 3;
    int idx = out_idx[j0 + jl];
    const unsigned short* src = (idx < NX) ? xT + (size_t)idx * NB
                                           : bufFin + (size_t)(idx - NX) * NB;
    int jcol = jl ^ (bq << 4);
#pragma unroll
    for (int k = 0; k < 8; ++k) {
      short8 v = *(const short8*)(src + b0 + bq * 64 + k * 8);
#pragma unroll
      for (int m = 0; m < 8; ++m)
        tile[bq * 64 + k * 8 + m][jcol] = (unsigned short)v[m];
    }
  }
  __syncthreads();
  {
    int j = t & 63, ws = t >> 6;
#pragma unroll
    for (int bb = 0; bb < 64; ++bb) {
      int b = bb * 4 + ws;
      int jc = j ^ ((b >> 6) << 4);
      out[(size_t)(b0 + b) * NOUT + j0 + j] = bf2f(tile[b][jc]);
    }
  }
}

// ---------------------------------------------------------------------------
extern "C" void kernel_launch(void* const* d_in, const int* in_sizes, int n_in,
                              void* d_out, int out_size, void* d_ws, size_t ws_size,
                              hipStream_t stream) {
  const float* x    = (const float*)d_in[0];
  const float* W    = (const float*)d_in[1];
  const int*   axon = (const int*)d_in[2];
  const int*   oidx = (const int*)d_in[3];
  float* out = (float*)d_out;

  const size_t XT_BYTES  = (size_t)NX * NB * 2;        // 33,570,816
  const size_t WB_BYTES  = (size_t)NC * NO * NA * 2;   //  1,048,576
  const size_t BUF_BYTES = (size_t)NROW * NB * 2;      // 67,108,864
  const size_t MASK_B    = 8192;
  if (ws_size < XT_BYTES + WB_BYTES + 2 * BUF_BYTES + 2 * MASK_B) return;

  char* p = (char*)d_ws;
  unsigned short* xT    = (unsigned short*)p;  p += XT_BYTES;
  unsigned short* Wb    = (unsigned short*)p;  p += WB_BYTES;
  unsigned short* bufA  = (unsigned short*)p;  p += BUF_BYTES;
  unsigned short* bufB  = (unsigned short*)p;  p += BUF_BYTES;
  unsigned char*  gmask = (unsigned char*)p;   p += MASK_B;
  unsigned char*  omask = (unsigned char*)p;

  prep_kernel<<<4360, 256, 0, stream>>>(x, W, xT, Wb);
  mask_kernel<<<1, 1024, 0, stream>>>(axon, oidx, gmask, omask);
  dim3 cg(NB / 512, NC);  // (8, 128): b-tile -> XCD
  cycle_kernel<0><<<cg, 512, 0, stream>>>(xT, Wb, bufB, bufA, axon, gmask, 1);
  cycle_kernel<0><<<cg, 512, 0, stream>>>(xT, Wb, bufA, bufB, axon, gmask, 0);
  cycle_kernel<0><<<cg, 512, 0, stream>>>(xT, Wb, bufB, bufA, axon, gmask, 0);
  cycle_kernel<1><<<cg, 512, 0, stream>>>(xT, Wb, bufA, bufB, axon, omask, 0);
  final_kernel<<<dim3(NOUT / 64, NB / 256), 256, 0, stream>>>(xT, bufB, oidx, out);
}

// Round 12
// 139.615 us; speedup vs baseline: 1.6668x; 1.1914x over previous
//
#include <hip/hip_runtime.h>

typedef __attribute__((ext_vector_type(8))) short short8;
typedef __attribute__((ext_vector_type(8))) __bf16 bf16x8;
typedef __attribute__((ext_vector_type(4))) float f32x4;
typedef __attribute__((ext_vector_type(4))) unsigned short ushort4_t;
typedef __attribute__((ext_vector_type(4))) unsigned int uint4_t;

#define NB   4096
#define NIN  4096
#define NX   4098
#define NC   128
#define NO   64
#define NA   64
#define NOUT 1024
#define NROW (NC * NO)

__device__ __forceinline__ unsigned short f2bf(float f) {
  unsigned b = __builtin_bit_cast(unsigned, f);
  b += 0x7FFFu + ((b >> 16) & 1u);
  return (unsigned short)(b >> 16);
}
__device__ __forceinline__ float bf2f(unsigned short u) {
  return __builtin_bit_cast(float, (unsigned)u << 16);
}

// ---------------------------------------------------------------------------
// prep: transpose x (B x NIN f32) -> xT (NX x NB bf16), W f32 -> bf16,
// and fill the zero/one constant rows. Runs at ~streaming roofline.
// ---------------------------------------------------------------------------
__global__ __launch_bounds__(256) void prep_kernel(
    const float* __restrict__ x, const float* __restrict__ W,
    unsigned short* __restrict__ xT, unsigned short* __restrict__ Wb) {
  int bid = blockIdx.x, t = threadIdx.x;
  if (bid < 4096) {
    __shared__ unsigned short tile[64][68];
    int b0 = (bid >> 6) << 6, n0 = (bid & 63) << 6;
    int r = t >> 4, c4 = (t & 15) << 2;
#pragma unroll
    for (int rr = 0; rr < 4; ++rr) {
      int row = r + rr * 16;
      float4 v = *(const float4*)(x + (size_t)(b0 + row) * NIN + n0 + c4);
      tile[row][c4 + 0] = f2bf(v.x);
      tile[row][c4 + 1] = f2bf(v.y);
      tile[row][c4 + 2] = f2bf(v.z);
      tile[row][c4 + 3] = f2bf(v.w);
    }
    __syncthreads();
#pragma unroll
    for (int rr = 0; rr < 4; ++rr) {
      int nl = r + rr * 16;
      ushort4_t o;
      o.x = tile[c4 + 0][nl];
      o.y = tile[c4 + 1][nl];
      o.z = tile[c4 + 2][nl];
      o.w = tile[c4 + 3][nl];
      *(ushort4_t*)(xT + (size_t)(n0 + nl) * NB + b0 + c4) = o;
    }
  } else if (bid < 4096 + 256) {
    size_t i0 = (size_t)(bid - 4096) * 2048 + (size_t)t * 8;
    float4 v0 = *(const float4*)(W + i0);
    float4 v1 = *(const float4*)(W + i0 + 4);
    ushort4_t a, b;
    a.x = f2bf(v0.x); a.y = f2bf(v0.y); a.z = f2bf(v0.z); a.w = f2bf(v0.w);
    b.x = f2bf(v1.x); b.y = f2bf(v1.y); b.z = f2bf(v1.z); b.w = f2bf(v1.w);
    *(ushort4_t*)(Wb + i0) = a;
    *(ushort4_t*)(Wb + i0 + 4) = b;
  } else {
    int e = (bid - 4352) * 1024 + t * 4;
    int row = e >> 12, col = e & 4095;
    unsigned short val = (row == 0) ? (unsigned short)0 : (unsigned short)0x3F80;
    ushort4_t o = {val, val, val, val};
    *(ushort4_t*)(xT + (size_t)(NIN + row) * NB + col) = o;
  }
}

// ---------------------------------------------------------------------------
// masks: gmask[r]=1 iff buffer row r is re-gathered by axon (read by any
// later cycle); omask[r]=1 iff the final gather reads row r.
// ---------------------------------------------------------------------------
__global__ __launch_bounds__(1024) void mask_kernel(
    const int* __restrict__ axon, const int* __restrict__ oidx,
    unsigned char* __restrict__ gmask, unsigned char* __restrict__ omask) {
  int t = threadIdx.x;
  for (int i = t; i < NROW; i += 1024) { gmask[i] = 0; omask[i] = 0; }
  __syncthreads();
  for (int i = t; i < NC * NA; i += 1024) {
    int idx = axon[i];
    if (idx >= NX) gmask[idx - NX] = 1;
  }
  if (t < NOUT) {
    int idx = oidx[t];
    if (idx >= NX) omask[idx - NX] = 1;
  }
}

// ---------------------------------------------------------------------------
// cycle (R8-verified best): BT=512, 512 thr (8 waves), grid (8,128) so each
// b-tile's 128 cores land on one XCD (linear = y*8+x, round-robin %8 = x).
// Stage: wave-uniform row ptrs, 1 KB contiguous loads; reg 8x8 transpose ->
// swizzled LDS [b][a]: addr_u16(b,a)=b*64+((a>>3)^(b&7)^((b>>5)&7))*8+(a&7).
// MFMA per wave over 64 b. Epilogue: acc -> OS LDS [64][520] -> full-row
// 1 KB stores, masked per row (gmask for cycles 1-3, omask for cycle 4).
// MODE 1 additionally skips MFMA for o-groups with no masked row.
//
// Structural constraint (R1-R11): ~50 MB/cycle of index-scattered reads +
// masked scattered-row writes runs at ~1.7-2.5 TB/s pattern-limited BW;
// phases sum serially (R7 ablation). Byte-reduction (fp8: R10 -93us),
// layout change (R9: -90us), and pipelining (R11: -27us) all regressed.
// ---------------------------------------------------------------------------
template <int MODE>
__global__ __launch_bounds__(512) void cycle_kernel(
    const unsigned short* __restrict__ xT, const unsigned short* __restrict__ Wb,
    const unsigned short* __restrict__ bufPrev, unsigned short* __restrict__ bufNext,
    const int* __restrict__ axon, const unsigned char* __restrict__ mask,
    int first) {
  __shared__ __align__(16) unsigned short SM[64 * 520];  // 66.6 KiB
  int c = blockIdx.y;
  int t = threadIdx.x;
  int b0 = blockIdx.x << 9;
  const int* arow = axon + (c << 6);

  int lane = t & 63, w = t >> 6;
  int ln = lane & 15, g = lane >> 4;

  // ---- stage: wave w owns rows a = w*8..w*8+7 (uniform ptrs); lane = 16 B
  {
    int ao = w, bo = lane;
    const int* ar = arow + ao * 8;
    uint4_t rows[8];
#pragma unroll
    for (int r = 0; r < 8; ++r) {
      int idx = ar[r];
      const unsigned short* s = nullptr;
      if (idx < NX)      s = xT + (size_t)idx * NB;
      else if (!first)   s = bufPrev + (size_t)(idx - NX) * NB;
      if (s) rows[r] = *(const uint4_t*)(s + b0 + bo * 8);
      else   rows[r] = (uint4_t)(0u);
    }
    unsigned lo[4][4], hi[4][4];
#pragma unroll
    for (int p = 0; p < 4; ++p)
#pragma unroll
      for (int k = 0; k < 4; ++k) {
        unsigned wi = rows[2 * p][k], wj = rows[2 * p + 1][k];
        lo[p][k] = __builtin_amdgcn_perm(wj, wi, 0x05040100u);
        hi[p][k] = __builtin_amdgcn_perm(wj, wi, 0x07060302u);
      }
#pragma unroll
    for (int e = 0; e < 8; ++e) {
      int k = e >> 1;
      uint4_t col;
      if (e & 1) { col[0] = hi[0][k]; col[1] = hi[1][k]; col[2] = hi[2][k]; col[3] = hi[3][k]; }
      else       { col[0] = lo[0][k]; col[1] = lo[1][k]; col[2] = lo[2][k]; col[3] = lo[3][k]; }
      int b = bo * 8 + e;
      int sw = ao ^ (b & 7) ^ ((b >> 5) & 7);
      *(uint4_t*)&SM[b * 64 + (sw << 3)] = col;
    }
  }
  __syncthreads();

  // ---- compute: wave w covers b-local [w*64, w*64+64) ----
  const unsigned short* wrow = Wb + ((size_t)c << 12);

  bool grp[4];
#pragma unroll
  for (int j = 0; j < 4; ++j) {
    if (MODE == 1) grp[j] = __any((int)(mask[(c << 6) + j * 16 + ln] != 0));
    else           grp[j] = true;
  }

  f32x4 acc[4][4];
#pragma unroll
  for (int i = 0; i < 4; ++i)
#pragma unroll
    for (int j = 0; j < 4; ++j) acc[i][j] = (f32x4)(0.f);

#pragma unroll
  for (int ks = 0; ks < 2; ++ks) {
    short8 ag[4];
#pragma unroll
    for (int i = 0; i < 4; ++i) {
      int bl = (w << 6) + (i << 4) + ln;
      int c8 = (ks << 2) + g;
      int sw = c8 ^ (bl & 7) ^ ((bl >> 5) & 7);
      ag[i] = *(const short8*)&SM[bl * 64 + (sw << 3)];
    }
#pragma unroll
    for (int j = 0; j < 4; ++j) {
      if (!grp[j]) continue;
      short8 bw = *(const short8*)(wrow + ((size_t)(j * 16 + ln) << 6) + ks * 32 + g * 8);
#pragma unroll
      for (int i = 0; i < 4; ++i)
        acc[i][j] = __builtin_amdgcn_mfma_f32_16x16x32_bf16(
            __builtin_bit_cast(bf16x8, ag[i]), __builtin_bit_cast(bf16x8, bw),
            acc[i][j], 0, 0, 0);
    }
  }

  // ---- epilogue: acc -> OS LDS [o=64][b=520-padded], then full-row stores
  __syncthreads();
#pragma unroll
  for (int j = 0; j < 4; ++j) {
    int o = j * 16 + ln;
#pragma unroll
    for (int i = 0; i < 4; ++i) {
      ushort4_t pk;
#pragma unroll
      for (int r = 0; r < 4; ++r) pk[r] = f2bf(fmaxf(acc[i][j][r], 0.f));
      *(ushort4_t*)&SM[o * 520 + (w << 6) + (i << 4) + (g << 2)] = pk;
    }
  }
  __syncthreads();
  // wave w stores rows {it*8+w}: 64 lanes x 16 B = 1 KB contiguous per row
#pragma unroll
  for (int it = 0; it < 8; ++it) {
    int row = it * 8 + w;
    if (mask[(c << 6) + row] == 0) continue;  // wave-uniform skip
    uint4_t v = *(const uint4_t*)&SM[row * 520 + (lane << 3)];
    *(uint4_t*)(bufNext + ((size_t)((c << 6) + row)) * NB + b0 + (lane << 3)) = v;
  }
}

// ---------------------------------------------------------------------------
// final: out[b][j] = f32(pool[out_idx[j]][b]); LDS transpose for coalescing.
// ---------------------------------------------------------------------------
__global__ __launch_bounds__(256) void final_kernel(
    const unsigned short* __restrict__ xT, const unsigned short* __restrict__ bufFin,
    const int* __restrict__ out_idx, float* __restrict__ out) {
  __shared__ unsigned short tile[256][66];
  int j0 = blockIdx.x << 6, b0 = blockIdx.y << 8;
  int t = threadIdx.x;
  {
    int jl = t >> 2, bq = t & 3;
    int idx = out_idx[j0 + jl];
    const unsigned short* src = (idx < NX) ? xT + (size_t)idx * NB
                                           : bufFin + (size_t)(idx - NX) * NB;
    int jcol = jl ^ (bq << 4);
#pragma unroll
    for (int k = 0; k < 8; ++k) {
      short8 v = *(const short8*)(src + b0 + bq * 64 + k * 8);
#pragma unroll
      for (int m = 0; m < 8; ++m)
        tile[bq * 64 + k * 8 + m][jcol] = (unsigned short)v[m];
    }
  }
  __syncthreads();
  {
    int j = t & 63, ws = t >> 6;
#pragma unroll
    for (int bb = 0; bb < 64; ++bb) {
      int b = bb * 4 + ws;
      int jc = j ^ ((b >> 6) << 4);
      out[(size_t)(b0 + b) * NOUT + j0 + j] = bf2f(tile[b][jc]);
    }
  }
}

// ---------------------------------------------------------------------------
extern "C" void kernel_launch(void* const* d_in, const int* in_sizes, int n_in,
                              void* d_out, int out_size, void* d_ws, size_t ws_size,
                              hipStream_t stream) {
  const float* x    = (const float*)d_in[0];
  const float* W    = (const float*)d_in[1];
  const int*   axon = (const int*)d_in[2];
  const int*   oidx = (const int*)d_in[3];
  float* out = (float*)d_out;

  const size_t XT_BYTES  = (size_t)NX * NB * 2;        // 33,570,816
  const size_t WB_BYTES  = (size_t)NC * NO * NA * 2;   //  1,048,576
  const size_t BUF_BYTES = (size_t)NROW * NB * 2;      // 67,108,864
  const size_t MASK_B    = 8192;
  if (ws_size < XT_BYTES + WB_BYTES + 2 * BUF_BYTES + 2 * MASK_B) return;

  char* p = (char*)d_ws;
  unsigned short* xT    = (unsigned short*)p;  p += XT_BYTES;
  unsigned short* Wb    = (unsigned short*)p;  p += WB_BYTES;
  unsigned short* bufA  = (unsigned short*)p;  p += BUF_BYTES;
  unsigned short* bufB  = (unsigned short*)p;  p += BUF_BYTES;
  unsigned char*  gmask = (unsigned char*)p;   p += MASK_B;
  unsigned char*  omask = (unsigned char*)p;

  prep_kernel<<<4360, 256, 0, stream>>>(x, W, xT, Wb);
  mask_kernel<<<1, 1024, 0, stream>>>(axon, oidx, gmask, omask);
  dim3 cg(NB / 512, NC);  // (8, 128): b-tile -> XCD, cores co-resident per XCD
  cycle_kernel<0><<<cg, 512, 0, stream>>>(xT, Wb, bufB, bufA, axon, gmask, 1);
  cycle_kernel<0><<<cg, 512, 0, stream>>>(xT, Wb, bufA, bufB, axon, gmask, 0);
  cycle_kernel<0><<<cg, 512, 0, stream>>>(xT, Wb, bufB, bufA, axon, gmask, 0);
  cycle_kernel<1><<<cg, 512, 0, stream>>>(xT, Wb, bufA, bufB, axon, omask, 0);
  final_kernel<<<dim3(NOUT / 64, NB / 256), 256, 0, stream>>>(xT, bufB, oidx, out);
}